// Round 2
// baseline (78.494 us; speedup 1.0000x reference)
//
#include <hip/hip_runtime.h>

// out[b] = sum_i s_i * ( h_i + sum_{j>i} J_ij * s_j ),  s = 1-2*bit in {+1,-1}
// vars: 32 singles then 496 pairs (i<j lexicographic) — canonical combinations
// order from setup_inputs(), baked in (validated by round-1 pass).
//
// Staging: wave-cooperative coalesced dword loads + __ballot bit-pack.
// Each wave iter: 64 consecutive int32s (256B dense) -> 64-bit ballot ->
// 2 packed row-masks -> LDS. Then thread t computes row (tile*256+t) from
// its 32-bit mask. Coefficients are wave-uniform -> scalar s_load batches.

constexpr int NB = 32;

__global__ __launch_bounds__(256) void KOBE_76948634075865_kernel(
    const int* __restrict__ bits,      // (n, 32) int32 0/1
    const float* __restrict__ vars,    // (528,) float32
    float* __restrict__ out,           // (n,) float32
    int n) {
  __shared__ unsigned smask[256];  // packed row masks for this tile

  const int t = threadIdx.x;
  const int lane = t & 63;
  const int w = t >> 6;  // wave id within block (0..3)

  const long long tile_row0 = (long long)blockIdx.x * 256;
  const long long tile_int0 = tile_row0 * NB;
  const long long total_ints = (long long)n * NB;
  const int* __restrict__ tile = bits + tile_int0;

  // Stage 256 rows (8192 ints) cooperatively: 32 iters x 256 threads x 1 dword.
#pragma unroll
  for (int k = 0; k < 32; ++k) {
    const int off = k * 256 + t;
    int v = 0;
    if (tile_int0 + off < total_ints) v = tile[off];
    const unsigned long long bal = __ballot(v != 0);  // bit l = lane l's bit
    // lanes 0..31 cover row r0 = k*8 + w*2, lanes 32..63 cover r0+1
    if ((lane & 31) == 0) {
      const int r0 = k * 8 + w * 2 + (lane >> 5);
      smask[r0] = (unsigned)(bal >> (lane & 32));
    }
  }
  __syncthreads();

  const long long row = tile_row0 + t;
  if (row >= n) return;

  const unsigned x = smask[t];  // stride-1 dword read: 2-way alias, free

  // s_i = +1.0f if bit i clear, -1.0f if set (sign-bit splice, 3 VALU each)
  float s[NB];
#pragma unroll
  for (int i = 0; i < NB; ++i) {
    s[i] = __int_as_float(0x3f800000u ^ ((x << (31 - i)) & 0x80000000u));
  }

  float acc = 0.f;
  int p = NB;  // running index into pair coefficients, constant-folded
#pragma unroll
  for (int i = 0; i < NB; ++i) {
    float gi = vars[i];  // h_i
#pragma unroll
    for (int j = i + 1; j < NB; ++j) {
      gi = fmaf(vars[p], s[j], gi);
      ++p;
    }
    acc = fmaf(s[i], gi, acc);
  }
  out[row] = acc;
}

extern "C" void kernel_launch(void* const* d_in, const int* in_sizes, int n_in,
                              void* d_out, int out_size, void* d_ws, size_t ws_size,
                              hipStream_t stream) {
  const int* bits = (const int*)d_in[0];     // (B, 32) int32
  const float* vars = (const float*)d_in[1]; // (528,) float32
  float* out = (float*)d_out;
  int n = in_sizes[0] / NB;  // batch rows
  int blocks = (n + 255) / 256;
  KOBE_76948634075865_kernel<<<blocks, 256, 0, stream>>>(bits, vars, out, n);
}

// Round 3
// 73.498 us; speedup vs baseline: 1.0680x; 1.0680x over previous
//
#include <hip/hip_runtime.h>

// out[b] = sum_i s_i * ( h_i + sum_{j>i} J_ij * s_j ),  s = 1-2*bit in {+1,-1}
// vars: 32 singles then 496 pairs (i<j lexicographic) — canonical
// itertools.combinations order from setup_inputs(), baked in (validated by
// round-1/2 passes).
//
// Round-3 structure: barrier-free (round-1 staging), but 2 rows per thread
// (rows t and t+n/2) with split gi accumulator chains. Rationale: 528 uniform
// coefficients exceed SGPR capacity -> compiler issues chunked s_loads with
// lgkmcnt waits; at ~2 waves/SIMD those stall. Two rows/thread doubles the
// independent FMA work per coefficient chunk (4 dep-chains), hiding the waits
// with ILP and halving per-row coefficient overhead.

constexpr int NB = 32;

__global__ __launch_bounds__(256) void KOBE_76948634075865_kernel(
    const int* __restrict__ bits,      // (n, 32) int32 0/1
    const float* __restrict__ vars,    // (528,) float32
    float* __restrict__ out,           // (n,) float32
    int n) {
  const int half = n >> 1;
  const int t = blockIdx.x * 256 + threadIdx.x;
  if (t >= half) return;

  // Two rows per thread: t and t+half. 8x int4 each (rows are 128B-aligned,
  // every fetched line fully consumed -> no HBM over-fetch).
  const int4* rowA = reinterpret_cast<const int4*>(bits) + (size_t)t * (NB / 4);
  const int4* rowB = rowA + (size_t)half * (NB / 4);

  float sa[NB], sb[NB];
#pragma unroll
  for (int k = 0; k < NB / 4; ++k) {
    int4 qa = rowA[k];
    int4 qb = rowB[k];
    // bit in {0,1}: s = +1.0f / -1.0f via sign-bit splice (2 VALU ops)
    sa[4 * k + 0] = __int_as_float(0x3f800000u ^ ((unsigned)qa.x << 31));
    sa[4 * k + 1] = __int_as_float(0x3f800000u ^ ((unsigned)qa.y << 31));
    sa[4 * k + 2] = __int_as_float(0x3f800000u ^ ((unsigned)qa.z << 31));
    sa[4 * k + 3] = __int_as_float(0x3f800000u ^ ((unsigned)qa.w << 31));
    sb[4 * k + 0] = __int_as_float(0x3f800000u ^ ((unsigned)qb.x << 31));
    sb[4 * k + 1] = __int_as_float(0x3f800000u ^ ((unsigned)qb.y << 31));
    sb[4 * k + 2] = __int_as_float(0x3f800000u ^ ((unsigned)qb.z << 31));
    sb[4 * k + 3] = __int_as_float(0x3f800000u ^ ((unsigned)qb.w << 31));
  }

  float accA = 0.f, accA2 = 0.f, accB = 0.f, accB2 = 0.f;
  int p = NB;  // running pair-coefficient index, constant-folded by unrolling
#pragma unroll
  for (int i = 0; i < NB; ++i) {
    const float hi = vars[i];
    float gA = hi, gA2 = 0.f;   // two interleaved chains per row for ILP
    float gB = hi, gB2 = 0.f;
#pragma unroll
    for (int j = i + 1; j < NB; ++j) {
      const float c = vars[p];
      ++p;
      if (((j - i) & 1) == 0) {
        gA = fmaf(c, sa[j], gA);
        gB = fmaf(c, sb[j], gB);
      } else {
        gA2 = fmaf(c, sa[j], gA2);
        gB2 = fmaf(c, sb[j], gB2);
      }
    }
    accA = fmaf(sa[i], gA, accA);
    accA2 = fmaf(sa[i], gA2, accA2);
    accB = fmaf(sb[i], gB, accB);
    accB2 = fmaf(sb[i], gB2, accB2);
  }
  out[t] = accA + accA2;
  out[t + half] = accB + accB2;
}

extern "C" void kernel_launch(void* const* d_in, const int* in_sizes, int n_in,
                              void* d_out, int out_size, void* d_ws, size_t ws_size,
                              hipStream_t stream) {
  const int* bits = (const int*)d_in[0];     // (B, 32) int32
  const float* vars = (const float*)d_in[1]; // (528,) float32
  float* out = (float*)d_out;
  int n = in_sizes[0] / NB;  // batch rows (131072)
  int threads_needed = n / 2;
  int blocks = (threads_needed + 255) / 256;
  KOBE_76948634075865_kernel<<<blocks, 256, 0, stream>>>(bits, vars, out, n);
}

// Round 4
// 71.281 us; speedup vs baseline: 1.1012x; 1.0311x over previous
//
#include <hip/hip_runtime.h>

// out[b] = sum_i s_i * ( h_i + sum_{j>i} J_ij * s_j ),  s = 1-2*bit in {+1,-1}
// vars: 32 singles then 496 pairs (i<j lexicographic) — canonical
// itertools.combinations order from setup_inputs(), baked in (validated by
// rounds 1-3 passing).
//
// Best-measured structure (round 1): 1 row/thread, 8x int4 strided loads,
// factored triangle (560 FMAs, coefficients via wave-uniform s_loads).
// Round-2 (ballot+LDS staging) and round-3 (2 rows/thread -> 1 wave/SIMD,
// lost latency hiding) both regressed; max TLP (2048 waves) wins here.

constexpr int NB = 32;

__global__ __launch_bounds__(256) void KOBE_76948634075865_kernel(
    const int* __restrict__ bits,      // (n, 32) int32 0/1
    const float* __restrict__ vars,    // (528,) float32
    float* __restrict__ out,           // (n,) float32
    int n) {
  int b = blockIdx.x * 256 + threadIdx.x;
  if (b >= n) return;

  // 8x int4 per row (128B, each fetched line fully consumed -> no over-fetch).
  const int4* row = reinterpret_cast<const int4*>(bits) + (size_t)b * (NB / 4);
  float s[NB];
#pragma unroll
  for (int k = 0; k < NB / 4; ++k) {
    int4 q = row[k];
    // bit in {0,1}: s = +1.0f / -1.0f via sign-bit splice (2 VALU ops)
    s[4 * k + 0] = __int_as_float(0x3f800000u ^ ((unsigned)q.x << 31));
    s[4 * k + 1] = __int_as_float(0x3f800000u ^ ((unsigned)q.y << 31));
    s[4 * k + 2] = __int_as_float(0x3f800000u ^ ((unsigned)q.z << 31));
    s[4 * k + 3] = __int_as_float(0x3f800000u ^ ((unsigned)q.w << 31));
  }

  float acc = 0.f;
  int p = NB;  // running pair-coefficient index, constant-folded by unrolling
#pragma unroll
  for (int i = 0; i < NB; ++i) {
    float gi = vars[i];  // h_i (sentinel partner s_32 == +1)
#pragma unroll
    for (int j = i + 1; j < NB; ++j) {
      gi = fmaf(vars[p], s[j], gi);
      ++p;
    }
    acc = fmaf(s[i], gi, acc);
  }
  out[b] = acc;
}

extern "C" void kernel_launch(void* const* d_in, const int* in_sizes, int n_in,
                              void* d_out, int out_size, void* d_ws, size_t ws_size,
                              hipStream_t stream) {
  const int* bits = (const int*)d_in[0];     // (B, 32) int32
  const float* vars = (const float*)d_in[1]; // (528,) float32
  float* out = (float*)d_out;
  int n = in_sizes[0] / NB;  // batch rows (131072)
  int blocks = (n + 255) / 256;
  KOBE_76948634075865_kernel<<<blocks, 256, 0, stream>>>(bits, vars, out, n);
}